// Round 8
// baseline (104.489 us; speedup 1.0000x reference)
//
#include <hip/hip_runtime.h>

// BuildCombinationsDim2: out[b,t,j] = x[b,t, idx[j]] where idx is the
// flattened list of k=2 combinations of F=32 features (lexicographic).
// ncr = 2*C(32,2) = 992. Pure gather along last axis; write-BW-bound.
// R8: exact fill-kernel clone. Output flattened to 32,505,856 f32x4
// groups; 524,288 threads grid-stride (8 MB compact moving window).
// Every wave instruction stores a full aligned 1 KB contiguous run,
// zero dead lanes, 62 exact iterations. Per iteration: row = G/248
// (magic-mul), g = G%248, closed-form combination inversion, 4 L1-hit
// gather loads, one nt float4 store. A computed memset.

#define FDIM 32
#define NCR 992            // k * C(F,2)
#define G_PER_ROW 248      // NCR / 4 f32x4 groups per row
#define BLOCK 256
#define GRID 2048          // 524,288 threads = 8192 waves, exact residency

typedef float f32x4 __attribute__((ext_vector_type(4)));

__global__ __launch_bounds__(BLOCK, 8)
void comb_gather_kernel(const float* __restrict__ x,
                        float* __restrict__ out,
                        int nrows) {
    const unsigned total   = (unsigned)nrows * G_PER_ROW;   // f32x4 groups
    const unsigned nthread = GRID * BLOCK;
    unsigned G = blockIdx.x * BLOCK + threadIdx.x;

    f32x4* outv = reinterpret_cast<f32x4*>(out);

    #pragma unroll 4
    for (; G < total; G += nthread) {
        // row = G / 248, g = G % 248  (compiler emits magic-mul for /248)
        const unsigned row = G / G_PER_ROW;
        const unsigned g   = G - row * G_PER_ROW;

        // Columns j = 4g..4g+3 -> combinations c0 = 2g, c1 = 2g+1.
        // Invert start(i) = i*(63-i)/2 in closed form with +-1 fixup.
        const int c0 = 2 * (int)g;
        float s = sqrtf(3969.0f - 8.0f * (float)c0);
        int i0 = (int)((63.0f - s) * 0.5f);
        if (i0 < 0) i0 = 0;
        int st0  = (i0 * (63 - i0)) >> 1;
        int stn0 = ((i0 + 1) * (62 - i0)) >> 1;
        if (stn0 <= c0) { i0++; st0 = stn0; stn0 = ((i0 + 1) * (62 - i0)) >> 1; }
        else if (st0 > c0) { i0--; stn0 = st0; st0 = (i0 * (63 - i0)) >> 1; }
        const int f0 = i0;
        const int f1 = c0 - st0 + i0 + 1;
        const int c1 = c0 + 1;
        int i1 = i0, st1 = st0;
        if (stn0 <= c1) { i1 = i0 + 1; st1 = stn0; }
        const int f2 = i1;
        const int f3 = c1 - st1 + i1 + 1;

        // Gather: one 128 B row per wave (1-2 cache lines), L1/L2-hit.
        const float* rowp = x + (size_t)row * FDIM;
        f32x4 v;
        v.x = rowp[f0];
        v.y = rowp[f1];
        v.z = rowp[f2];
        v.w = rowp[f3];

        __builtin_nontemporal_store(v, outv + G);   // aligned 1 KB per wave inst
    }
}

extern "C" void kernel_launch(void* const* d_in, const int* in_sizes, int n_in,
                              void* d_out, int out_size, void* d_ws, size_t ws_size,
                              hipStream_t stream) {
    const float* x  = (const float*)d_in[0];
    float* out      = (float*)d_out;
    int nrows = in_sizes[0] / FDIM;                       // 32*4096 = 131072
    hipLaunchKernelGGL(comb_gather_kernel, dim3(GRID), dim3(BLOCK), 0, stream,
                       x, out, nrows);
}